// Round 7
// baseline (220.443 us; speedup 1.0000x reference)
//
#include <hip/hip_runtime.h>
#include <hip/hip_bf16.h>
#include <cstdint>
#include <cstddef>

#define B_ 2
#define N_ 2048
#define D_ 1024
#define H_ 16
#define DH_ 64
#define XYROWS 4095   /* N + (N-1) */
#define NL 12         /* self + 11 tree neighbors */
#define QKVN 3072     /* packed Q|K|V projection width */

typedef __attribute__((ext_vector_type(8))) short bf16x8;
typedef __attribute__((ext_vector_type(4))) float f32x4;

__device__ __forceinline__ float asf(unsigned int u) {
    union { unsigned int i; float f; } v; v.i = u; return v.f;
}
__device__ __forceinline__ unsigned short f2bf(float f) {
    union { float f; unsigned int i; } v; v.f = f;
    unsigned int u = v.i;
    unsigned int r = u + 0x7FFFu + ((u >> 16) & 1u);   // RNE
    return (unsigned short)(r >> 16);
}

// load 8 bf16 (16B) -> 8 fp32
__device__ __forceinline__ void ld8(const unsigned short* p, float* o) {
    uint4 u = *(const uint4*)p;
    o[0] = asf(u.x << 16); o[1] = asf(u.x & 0xffff0000u);
    o[2] = asf(u.y << 16); o[3] = asf(u.y & 0xffff0000u);
    o[4] = asf(u.z << 16); o[5] = asf(u.z & 0xffff0000u);
    o[6] = asf(u.w << 16); o[7] = asf(u.w & 0xffff0000u);
}

// async global->LDS 16B per lane; lds base wave-uniform, HW scatters lane l
// to base + l*16.
__device__ __forceinline__ void gload_lds16(const unsigned short* g, unsigned short* l) {
    __builtin_amdgcn_global_load_lds(
        (const __attribute__((address_space(1))) unsigned int*)g,
        (__attribute__((address_space(3))) unsigned int*)l,
        16, 0, 0);
}

// ---- fused prep: build xy (bf16) + convert all four weight matrices ----
__global__ void prep_kernel(const float* __restrict__ q, const float* __restrict__ y,
                            const float* __restrict__ Wq, const float* __restrict__ Wk,
                            const float* __restrict__ Wv, const float* __restrict__ Wo,
                            unsigned short* __restrict__ xy,
                            unsigned short* __restrict__ wqkv, unsigned short* __restrict__ wob) {
    int c = blockIdx.x * blockDim.x + threadIdx.x;   // chunk of 8 elems
    constexpr int TOTAL_XY = B_ * XYROWS * (D_ / 8); // 1048320
    constexpr int TOTAL_W  = 4 * 131072;             // 524288
    if (c >= TOTAL_XY + TOTAL_W) return;
    const float* src;
    unsigned short* dst;
    if (c < TOTAL_XY) {
        int col8 = (c & (D_ / 8 - 1)) * 8;
        int rg = c >> 7;                              // global row 0..B*4095-1
        int b = (rg >= XYROWS) ? 1 : 0;
        int r = rg - b * XYROWS;
        if (r < N_) src = q + ((size_t)b * N_ + r) * D_ + col8;
        else        src = y + ((size_t)b * (N_ - 1) + (r - N_)) * D_ + col8;
        dst = xy + (size_t)rg * D_ + col8;
    } else {
        int idx = c - TOTAL_XY;
        int which = idx >> 17;
        int sub = idx & 131071;
        const float* w = (which == 0) ? Wq : (which == 1) ? Wk : (which == 2) ? Wv : Wo;
        src = w + (size_t)sub * 8;
        dst = ((which < 3) ? (wqkv + (size_t)which * D_ * D_) : wob) + (size_t)sub * 8;
    }
    float4 a = *(const float4*)(src);
    float4 bb = *(const float4*)(src + 4);
    union { unsigned short us[8]; uint4 u4; } o;
    o.us[0] = f2bf(a.x);  o.us[1] = f2bf(a.y);  o.us[2] = f2bf(a.z);  o.us[3] = f2bf(a.w);
    o.us[4] = f2bf(bb.x); o.us[5] = f2bf(bb.y); o.us[6] = f2bf(bb.z); o.us[7] = f2bf(bb.w);
    *(uint4*)(dst) = o.u4;
}

// --------------------------- bf16 GEMM: C = A @ W^T -----------------------
// A: M x 1024 bf16 row-major; W: Nn x 1024 bf16 row-major.
// BM x 128 block tile, 4 waves (2x2), (BM/2)x64 per wave via MFMA 16x16x32.
// BM=128 is the measured sweet spot (R5/R6: BM=192 regressed — occupancy &
// barrier phase-lock beat the intensity gain).
// *** gridDim.x MUST be a multiple of 8 ***: XCD = linear-block-id % 8, so a
// multiple-of-8 grid.x pins each x-tile's A-slice to one XCD L2 across all
// col-tiles (R5 lesson: grid.x=43 scattered x over XCDs -> 8x A-fetch).
// Staging: global_load_lds width=16, XOR-swizzled chunk order (0 bank conflicts).
// NT: non-temporal C-stores — C is write-once; keeping it out of L2 protects
// the XCD-resident A-slice (R4 FETCH 41.5 MB vs ~22 ideal = A evicted once).
// QSKIP: skip Q columns (col0<1024) on row tiles holding only y-positions.
template<int BM, bool OUTF32, bool BIAS, bool QSKIP>
__global__ __launch_bounds__(256, 2)
void gemm_bt(const unsigned short* __restrict__ A, const unsigned short* __restrict__ W,
             void* __restrict__ Cv, const float* __restrict__ bias, int M, int Nn) {
    constexpr int K = 1024, BK = 64;
    constexpr int IM = BM / 32;          // mfma row-tiles per wave
    __shared__ __align__(16) unsigned short la[BM * 64];
    __shared__ __align__(16) unsigned short lb[128 * 64];

    int row0 = blockIdx.x * BM;
    if (row0 >= M) return;                  // grid.x padded to a multiple of 8
    int col0 = blockIdx.y * 128;
    if (QSKIP && col0 < 1024) {
        int t = blockIdx.x;                 // y-only row tiles for BM=128:
        if ((t >= 16 && t <= 30) || t >= 48) return;
    }
    int tid = threadIdx.x;
    int wave = tid >> 6, lane = tid & 63;
    int wm = wave >> 1, wn = wave & 1;
    int q4 = lane >> 4, r = lane & 15;

    // staging: lane l supplies row l/8 of its segment; fetched chunk is
    // XOR-swizzled by the row's low 3 bits.
    int rsub = lane >> 3;                         // 0..7
    int csw = ((lane & 7) ^ rsub) * 8;            // swizzled source chunk col

    f32x4 acc[IM][4];
    f32x4 zero = {0.f, 0.f, 0.f, 0.f};
#pragma unroll
    for (int i = 0; i < IM; i++)
#pragma unroll
        for (int j = 0; j < 4; j++) acc[i][j] = zero;

    for (int k0 = 0; k0 < K; k0 += BK) {
#pragma unroll
        for (int p = 0; p < IM; p++) {            // A: 4*IM = BM/8 segments
            int seg = wave * IM + p;
            int ar = row0 + seg * 8 + rsub; if (ar >= M) ar = M - 1;
            gload_lds16(A + (size_t)ar * K + k0 + csw, &la[seg * 512]);
        }
#pragma unroll
        for (int p = 0; p < 4; p++) {             // B: 16 segs, 4 per wave
            int seg = wave * 4 + p;
            gload_lds16(W + (size_t)(col0 + seg * 8 + rsub) * K + k0 + csw, &lb[seg * 512]);
        }
        __syncthreads();
#pragma unroll
        for (int ks = 0; ks < 2; ks++) {
            int cidx = ks * 4 + q4;
            bf16x8 af[IM], bfv[4];
#pragma unroll
            for (int j = 0; j < 4; j++) {
                int rb = wn * 64 + j * 16 + r;
                bfv[j] = *(const bf16x8*)(&lb[rb * 64 + ((cidx ^ (rb & 7)) << 3)]);
            }
#pragma unroll
            for (int i = 0; i < IM; i++) {
                int rr = wm * (BM / 2) + i * 16 + r;
                af[i] = *(const bf16x8*)(&la[rr * 64 + ((cidx ^ (rr & 7)) << 3)]);
            }
#pragma unroll
            for (int i = 0; i < IM; i++)
#pragma unroll
                for (int j = 0; j < 4; j++)
                    acc[i][j] = __builtin_amdgcn_mfma_f32_16x16x32_bf16(af[i], bfv[j], acc[i][j], 0, 0, 0);
        }
        __syncthreads();
    }

    float bv[4];
    if (BIAS) {
#pragma unroll
        for (int j = 0; j < 4; j++) bv[j] = bias[col0 + wn * 64 + j * 16 + r];
    }
#pragma unroll
    for (int i = 0; i < IM; i++) {
#pragma unroll
        for (int j = 0; j < 4; j++) {
            int col = col0 + wn * 64 + j * 16 + r;
#pragma unroll
            for (int reg = 0; reg < 4; reg++) {
                int row = row0 + wm * (BM / 2) + i * 16 + q4 * 4 + reg;
                if (row < M) {
                    float v = acc[i][j][reg];
                    if (BIAS) v += bv[j];
                    if (OUTF32) {
                        __builtin_nontemporal_store(
                            v, ((float*)Cv) + (size_t)row * Nn + col);
                    } else {
                        __builtin_nontemporal_store(
                            f2bf(v), ((unsigned short*)Cv) + (size_t)row * Nn + col);
                    }
                }
            }
        }
    }
}

// ----------------------- hierarchical sparse attention --------------------
// One block per (query-pair, batch); queries 2i,2i+1 share all 12 rows.
// QKV layout: per xy-row, 3072 cols = [Q | K | V].
__global__ __launch_bounds__(256)
void attn_kernel(const unsigned short* __restrict__ QKV, unsigned short* __restrict__ O) {
    int t = threadIdx.x;
    int half = t >> 7;           // which query of the pair
    int c = t & 127;             // 8-dim chunk 0..127
    int b = blockIdx.y;
    int n = blockIdx.x * 2 + half;

    int rows[NL];
    rows[0] = n;
    int cur = n ^ 1;
    rows[1] = cur;
#pragma unroll
    for (int l = 1; l < 11; l++) {
        cur = ((cur >> 1) + N_) ^ 1;
        rows[l + 1] = cur;
    }

    const unsigned short* base = QKV + (size_t)b * XYROWS * QKVN;
    size_t c8 = (size_t)c * 8;

    float q[8];
    ld8(base + (size_t)n * QKVN + c8, q);

    float logits[NL];
#pragma unroll
    for (int j = 0; j < NL; j++) {
        float kv[8];
        ld8(base + (size_t)rows[j] * QKVN + D_ + c8, kv);
        float p = 0.f;
#pragma unroll
        for (int e = 0; e < 8; e++) p = fmaf(q[e], kv[e], p);
        p += __shfl_xor(p, 1);
        p += __shfl_xor(p, 2);
        p += __shfl_xor(p, 4);
        logits[j] = p * 0.125f;   // 1/sqrt(64)
    }

    float mx = logits[0];
#pragma unroll
    for (int j = 1; j < NL; j++) mx = fmaxf(mx, logits[j]);
    float s = 0.f, w[NL];
#pragma unroll
    for (int j = 0; j < NL; j++) { w[j] = __expf(logits[j] - mx); s += w[j]; }
    float inv = 1.f / s;

    float acc[8] = {0.f, 0.f, 0.f, 0.f, 0.f, 0.f, 0.f, 0.f};
#pragma unroll
    for (int j = 0; j < NL; j++) {
        float vv[8];
        ld8(base + (size_t)rows[j] * QKVN + 2 * D_ + c8, vv);
        float wj = w[j] * inv;
#pragma unroll
        for (int e = 0; e < 8; e++) acc[e] = fmaf(wj, vv[e], acc[e]);
    }

    union { unsigned short us[8]; uint4 u4; } o;
#pragma unroll
    for (int e = 0; e < 8; e++) o.us[e] = f2bf(acc[e]);
    *(uint4*)(O + ((size_t)b * N_ + n) * D_ + c8) = o.u4;
}

extern "C" void kernel_launch(void* const* d_in, const int* in_sizes, int n_in,
                              void* d_out, int out_size, void* d_ws, size_t ws_size,
                              hipStream_t stream) {
    const float* query = (const float*)d_in[0];
    // d_in[1] (key), d_in[2] (value) are unused by the reference
    const float* y  = (const float*)d_in[3];
    const float* Wq = (const float*)d_in[4];
    const float* Wk = (const float*)d_in[5];
    const float* Wv = (const float*)d_in[6];
    const float* Wo = (const float*)d_in[7];
    const float* bo = (const float*)d_in[8];
    float* out = (float*)d_out;

    char* ws = (char*)d_ws;
    size_t off = 0;
    auto alloc = [&](size_t bytes) {
        void* p = ws + off; off += (bytes + 255) & ~(size_t)255; return p;
    };
    unsigned short* xy   = (unsigned short*)alloc((size_t)B_ * XYROWS * D_ * 2 + 8192);  // pad: OOB-clamped tile rows
    unsigned short* wqkv = (unsigned short*)alloc((size_t)QKVN * D_ * 2);
    unsigned short* wob  = (unsigned short*)alloc((size_t)D_ * D_ * 2);
    unsigned short* QKV  = (unsigned short*)alloc((size_t)B_ * XYROWS * QKVN * 2 + 16384);
    unsigned short* At   = (unsigned short*)alloc((size_t)B_ * N_ * D_ * 2);

    // 1. fused prep: xy (bf16) + all weight conversions
    prep_kernel<<<6144, 256, 0, stream>>>(query, y, Wq, Wk, Wv, Wo, xy, wqkv, wob);

    // 2. fused QKV projection, BM=128; grid.x=64 (mult of 8 -> XCD-pinned
    //    A-slices); QSKIP drops Q cols on y-only row tiles; NT C-stores.
    {
        dim3 g(64, QKVN / 128);
        gemm_bt<128, false, false, true><<<g, 256, 0, stream>>>(
            xy, wqkv, QKV, nullptr, B_ * XYROWS, QKVN);
    }
    // 3. hierarchical attention (paired queries)
    {
        dim3 g(N_ / 2, B_);
        attn_kernel<<<g, 256, 0, stream>>>(QKV, At);
    }
    // 4. output projection + bias (fp32 out), BM=64 -> grid.x 64 (mult of 8)
    {
        dim3 g((B_ * N_) / 64, D_ / 128);
        gemm_bt<64, true, true, false><<<g, 256, 0, stream>>>(At, wob, out, bo, B_ * N_, D_);
    }
}

// Round 8
// 201.598 us; speedup vs baseline: 1.0935x; 1.0935x over previous
//
#include <hip/hip_runtime.h>
#include <hip/hip_bf16.h>
#include <cstdint>
#include <cstddef>

#define B_ 2
#define N_ 2048
#define D_ 1024
#define H_ 16
#define DH_ 64
#define XYROWS 4095   /* N + (N-1) */
#define NL 12         /* self + 11 tree neighbors */
#define QKVN 3072     /* packed Q|K|V projection width */

typedef __attribute__((ext_vector_type(8))) short bf16x8;
typedef __attribute__((ext_vector_type(4))) float f32x4;

__device__ __forceinline__ float asf(unsigned int u) {
    union { unsigned int i; float f; } v; v.i = u; return v.f;
}
__device__ __forceinline__ unsigned short f2bf(float f) {
    union { float f; unsigned int i; } v; v.f = f;
    unsigned int u = v.i;
    unsigned int r = u + 0x7FFFu + ((u >> 16) & 1u);   // RNE
    return (unsigned short)(r >> 16);
}

// load 8 bf16 (16B) -> 8 fp32
__device__ __forceinline__ void ld8(const unsigned short* p, float* o) {
    uint4 u = *(const uint4*)p;
    o[0] = asf(u.x << 16); o[1] = asf(u.x & 0xffff0000u);
    o[2] = asf(u.y << 16); o[3] = asf(u.y & 0xffff0000u);
    o[4] = asf(u.z << 16); o[5] = asf(u.z & 0xffff0000u);
    o[6] = asf(u.w << 16); o[7] = asf(u.w & 0xffff0000u);
}

// async global->LDS 16B per lane; lds base wave-uniform, HW scatters lane l
// to base + l*16.
__device__ __forceinline__ void gload_lds16(const unsigned short* g, unsigned short* l) {
    __builtin_amdgcn_global_load_lds(
        (const __attribute__((address_space(1))) unsigned int*)g,
        (__attribute__((address_space(3))) unsigned int*)l,
        16, 0, 0);
}

// ---- fused prep: build xy (bf16) + convert all four weight matrices ----
__global__ void prep_kernel(const float* __restrict__ q, const float* __restrict__ y,
                            const float* __restrict__ Wq, const float* __restrict__ Wk,
                            const float* __restrict__ Wv, const float* __restrict__ Wo,
                            unsigned short* __restrict__ xy,
                            unsigned short* __restrict__ wqkv, unsigned short* __restrict__ wob) {
    int c = blockIdx.x * blockDim.x + threadIdx.x;   // chunk of 8 elems
    constexpr int TOTAL_XY = B_ * XYROWS * (D_ / 8); // 1048320
    constexpr int TOTAL_W  = 4 * 131072;             // 524288
    if (c >= TOTAL_XY + TOTAL_W) return;
    const float* src;
    unsigned short* dst;
    if (c < TOTAL_XY) {
        int col8 = (c & (D_ / 8 - 1)) * 8;
        int rg = c >> 7;                              // global row 0..B*4095-1
        int b = (rg >= XYROWS) ? 1 : 0;
        int r = rg - b * XYROWS;
        if (r < N_) src = q + ((size_t)b * N_ + r) * D_ + col8;
        else        src = y + ((size_t)b * (N_ - 1) + (r - N_)) * D_ + col8;
        dst = xy + (size_t)rg * D_ + col8;
    } else {
        int idx = c - TOTAL_XY;
        int which = idx >> 17;
        int sub = idx & 131071;
        const float* w = (which == 0) ? Wq : (which == 1) ? Wk : (which == 2) ? Wv : Wo;
        src = w + (size_t)sub * 8;
        dst = ((which < 3) ? (wqkv + (size_t)which * D_ * D_) : wob) + (size_t)sub * 8;
    }
    float4 a = *(const float4*)(src);
    float4 bb = *(const float4*)(src + 4);
    union { unsigned short us[8]; uint4 u4; } o;
    o.us[0] = f2bf(a.x);  o.us[1] = f2bf(a.y);  o.us[2] = f2bf(a.z);  o.us[3] = f2bf(a.w);
    o.us[4] = f2bf(bb.x); o.us[5] = f2bf(bb.y); o.us[6] = f2bf(bb.z); o.us[7] = f2bf(bb.w);
    *(uint4*)(dst) = o.u4;
}

// --------------------------- bf16 GEMM: C = A @ W^T -----------------------
// A: M x 1024 bf16 row-major; W: Nn x 1024 bf16 row-major.
// BM x 128 block tile, 4 waves (2x2), (BM/2)x64 per wave via MFMA 16x16x32.
// BM=128 is the measured sweet spot (R5/R6: BM=192 regressed).
// *** gridDim.x MUST be a multiple of 8 ***: XCD = linear-block-id % 8 pins
// each x-tile's A-slice to one XCD L2 (R5: grid.x=43 -> 8x A-fetch).
// Staging: global_load_lds width=16, XOR-swizzled chunk order (0 bank conflicts).
// Stores: PLAIN scalar stores — R7 showed non-temporal scalar stores break L2
// write-combining (WRITE_SIZE 41->94 MB, +10 us). NT only for full-line stores.
// QSKIP: skip Q columns (col0<1024) on row tiles holding only y-positions.
template<int BM, bool OUTF32, bool BIAS, bool QSKIP>
__global__ __launch_bounds__(256, 2)
void gemm_bt(const unsigned short* __restrict__ A, const unsigned short* __restrict__ W,
             void* __restrict__ Cv, const float* __restrict__ bias, int M, int Nn) {
    constexpr int K = 1024, BK = 64;
    constexpr int IM = BM / 32;          // mfma row-tiles per wave
    __shared__ __align__(16) unsigned short la[BM * 64];
    __shared__ __align__(16) unsigned short lb[128 * 64];

    int row0 = blockIdx.x * BM;
    if (row0 >= M) return;                  // grid.x padded to a multiple of 8
    int col0 = blockIdx.y * 128;
    if (QSKIP && col0 < 1024) {
        int t = blockIdx.x;                 // y-only row tiles for BM=128:
        if ((t >= 16 && t <= 30) || t >= 48) return;
    }
    int tid = threadIdx.x;
    int wave = tid >> 6, lane = tid & 63;
    int wm = wave >> 1, wn = wave & 1;
    int q4 = lane >> 4, r = lane & 15;

    // staging: lane l supplies row l/8 of its segment; fetched chunk is
    // XOR-swizzled by the row's low 3 bits.
    int rsub = lane >> 3;                         // 0..7
    int csw = ((lane & 7) ^ rsub) * 8;            // swizzled source chunk col

    f32x4 acc[IM][4];
    f32x4 zero = {0.f, 0.f, 0.f, 0.f};
#pragma unroll
    for (int i = 0; i < IM; i++)
#pragma unroll
        for (int j = 0; j < 4; j++) acc[i][j] = zero;

    for (int k0 = 0; k0 < K; k0 += BK) {
#pragma unroll
        for (int p = 0; p < IM; p++) {            // A: 4*IM = BM/8 segments
            int seg = wave * IM + p;
            int ar = row0 + seg * 8 + rsub; if (ar >= M) ar = M - 1;
            gload_lds16(A + (size_t)ar * K + k0 + csw, &la[seg * 512]);
        }
#pragma unroll
        for (int p = 0; p < 4; p++) {             // B: 16 segs, 4 per wave
            int seg = wave * 4 + p;
            gload_lds16(W + (size_t)(col0 + seg * 8 + rsub) * K + k0 + csw, &lb[seg * 512]);
        }
        __syncthreads();
#pragma unroll
        for (int ks = 0; ks < 2; ks++) {
            int cidx = ks * 4 + q4;
            bf16x8 af[IM], bfv[4];
#pragma unroll
            for (int j = 0; j < 4; j++) {
                int rb = wn * 64 + j * 16 + r;
                bfv[j] = *(const bf16x8*)(&lb[rb * 64 + ((cidx ^ (rb & 7)) << 3)]);
            }
#pragma unroll
            for (int i = 0; i < IM; i++) {
                int rr = wm * (BM / 2) + i * 16 + r;
                af[i] = *(const bf16x8*)(&la[rr * 64 + ((cidx ^ (rr & 7)) << 3)]);
            }
#pragma unroll
            for (int i = 0; i < IM; i++)
#pragma unroll
                for (int j = 0; j < 4; j++)
                    acc[i][j] = __builtin_amdgcn_mfma_f32_16x16x32_bf16(af[i], bfv[j], acc[i][j], 0, 0, 0);
        }
        __syncthreads();
    }

    float bv[4];
    if (BIAS) {
#pragma unroll
        for (int j = 0; j < 4; j++) bv[j] = bias[col0 + wn * 64 + j * 16 + r];
    }
#pragma unroll
    for (int i = 0; i < IM; i++) {
#pragma unroll
        for (int j = 0; j < 4; j++) {
            int col = col0 + wn * 64 + j * 16 + r;
#pragma unroll
            for (int reg = 0; reg < 4; reg++) {
                int row = row0 + wm * (BM / 2) + i * 16 + q4 * 4 + reg;
                if (row < M) {
                    float v = acc[i][j][reg];
                    if (BIAS) v += bv[j];
                    if (OUTF32)
                        ((float*)Cv)[(size_t)row * Nn + col] = v;
                    else
                        ((unsigned short*)Cv)[(size_t)row * Nn + col] = f2bf(v);
                }
            }
        }
    }
}

// ----------------------- hierarchical sparse attention --------------------
// Queries 2i and 2i+1 share the SAME 12-row set (level-0 neighbors are each
// other, parent chain identical; softmax is order-invariant). Each THREAD
// handles BOTH queries of a pair for one 8-dim chunk: K/V chunks are loaded
// once and used twice (halves load traffic vs one-query-per-thread).
// Block = 256 threads = 2 pairs (t>>7 picks pair), c = t&127 picks chunk.
__global__ __launch_bounds__(256)
void attn_kernel(const unsigned short* __restrict__ QKV, unsigned short* __restrict__ O) {
    int t = threadIdx.x;
    int pi = (blockIdx.x << 1) | (t >> 7);   // pair index 0..1023
    int c = t & 127;                          // 8-dim chunk
    int b = blockIdx.y;
    int n0 = pi * 2;                          // even query of the pair

    int rows[NL];
    rows[0] = n0;
    rows[1] = n0 + 1;
    int cur = n0 + 1;
#pragma unroll
    for (int l = 1; l < 11; l++) {
        cur = ((cur >> 1) + N_) ^ 1;
        rows[l + 1] = cur;
    }

    const unsigned short* base = QKV + (size_t)b * XYROWS * QKVN;
    size_t c8 = (size_t)c * 8;

    float q0[8], q1[8];
    ld8(base + (size_t)n0 * QKVN + c8, q0);
    ld8(base + ((size_t)n0 + 1) * QKVN + c8, q1);

    float l0[NL], l1[NL];
#pragma unroll
    for (int j = 0; j < NL; j++) {
        float kv[8];
        ld8(base + (size_t)rows[j] * QKVN + D_ + c8, kv);
        float p0 = 0.f, p1 = 0.f;
#pragma unroll
        for (int e = 0; e < 8; e++) { p0 = fmaf(q0[e], kv[e], p0); p1 = fmaf(q1[e], kv[e], p1); }
        p0 += __shfl_xor(p0, 1); p1 += __shfl_xor(p1, 1);
        p0 += __shfl_xor(p0, 2); p1 += __shfl_xor(p1, 2);
        p0 += __shfl_xor(p0, 4); p1 += __shfl_xor(p1, 4);
        l0[j] = p0 * 0.125f;   // 1/sqrt(64)
        l1[j] = p1 * 0.125f;
    }

    float mx0 = l0[0], mx1 = l1[0];
#pragma unroll
    for (int j = 1; j < NL; j++) { mx0 = fmaxf(mx0, l0[j]); mx1 = fmaxf(mx1, l1[j]); }
    float s0 = 0.f, s1 = 0.f;
#pragma unroll
    for (int j = 0; j < NL; j++) {
        l0[j] = __expf(l0[j] - mx0); s0 += l0[j];
        l1[j] = __expf(l1[j] - mx1); s1 += l1[j];
    }
    float i0 = 1.f / s0, i1 = 1.f / s1;

    float a0[8] = {0,0,0,0,0,0,0,0}, a1[8] = {0,0,0,0,0,0,0,0};
#pragma unroll
    for (int j = 0; j < NL; j++) {
        float vv[8];
        ld8(base + (size_t)rows[j] * QKVN + 2 * D_ + c8, vv);
        float w0 = l0[j] * i0, w1 = l1[j] * i1;
#pragma unroll
        for (int e = 0; e < 8; e++) { a0[e] = fmaf(w0, vv[e], a0[e]); a1[e] = fmaf(w1, vv[e], a1[e]); }
    }

    union { unsigned short us[8]; uint4 u4; } o0, o1;
#pragma unroll
    for (int e = 0; e < 8; e++) { o0.us[e] = f2bf(a0[e]); o1.us[e] = f2bf(a1[e]); }
    size_t obase = ((size_t)b * N_ + n0) * D_ + c8;
    *(uint4*)(O + obase) = o0.u4;
    *(uint4*)(O + obase + D_) = o1.u4;
}

extern "C" void kernel_launch(void* const* d_in, const int* in_sizes, int n_in,
                              void* d_out, int out_size, void* d_ws, size_t ws_size,
                              hipStream_t stream) {
    const float* query = (const float*)d_in[0];
    // d_in[1] (key), d_in[2] (value) are unused by the reference
    const float* y  = (const float*)d_in[3];
    const float* Wq = (const float*)d_in[4];
    const float* Wk = (const float*)d_in[5];
    const float* Wv = (const float*)d_in[6];
    const float* Wo = (const float*)d_in[7];
    const float* bo = (const float*)d_in[8];
    float* out = (float*)d_out;

    char* ws = (char*)d_ws;
    size_t off = 0;
    auto alloc = [&](size_t bytes) {
        void* p = ws + off; off += (bytes + 255) & ~(size_t)255; return p;
    };
    unsigned short* xy   = (unsigned short*)alloc((size_t)B_ * XYROWS * D_ * 2 + 8192);  // pad: OOB-clamped tile rows
    unsigned short* wqkv = (unsigned short*)alloc((size_t)QKVN * D_ * 2);
    unsigned short* wob  = (unsigned short*)alloc((size_t)D_ * D_ * 2);
    unsigned short* QKV  = (unsigned short*)alloc((size_t)B_ * XYROWS * QKVN * 2 + 16384);
    unsigned short* At   = (unsigned short*)alloc((size_t)B_ * N_ * D_ * 2);

    // 1. fused prep: xy (bf16) + all weight conversions
    prep_kernel<<<6144, 256, 0, stream>>>(query, y, Wq, Wk, Wv, Wo, xy, wqkv, wob);

    // 2. fused QKV projection, BM=128; grid.x=64 (mult of 8 -> XCD-pinned
    //    A-slices); QSKIP drops Q cols on y-only row tiles; plain stores.
    {
        dim3 g(64, QKVN / 128);
        gemm_bt<128, false, false, true><<<g, 256, 0, stream>>>(
            xy, wqkv, QKV, nullptr, B_ * XYROWS, QKVN);
    }
    // 3. hierarchical attention: 2 pairs/block, both queries per thread
    {
        dim3 g(N_ / 4, B_);
        attn_kernel<<<g, 256, 0, stream>>>(QKV, At);
    }
    // 4. output projection + bias (fp32 out), BM=64 -> grid.x 64 (mult of 8)
    {
        dim3 g((B_ * N_) / 64, D_ / 128);
        gemm_bt<64, true, true, false><<<g, 256, 0, stream>>>(At, wob, out, bo, B_ * N_, D_);
    }
}